// Round 5
// baseline (528.086 us; speedup 1.0000x reference)
//
#include <hip/hip_runtime.h>
#include <hip/hip_bf16.h>

typedef __bf16 bf16_t;
typedef __bf16 bf16x4_t __attribute__((ext_vector_type(4)));
typedef __bf16 bf16x8_t __attribute__((ext_vector_type(8)));
typedef float f32x4_t __attribute__((ext_vector_type(4)));

typedef __attribute__((address_space(1))) void gvoid_t;
typedef __attribute__((address_space(3))) void svoid_t;

__device__ __forceinline__ void gload_lds16(const void* g, void* s) {
    // async global->LDS, 16B per lane; LDS dest = wave-uniform base + lane*16
    __builtin_amdgcn_global_load_lds((gvoid_t*)g, (svoid_t*)s, 16, 0, 0);
}

// Raw barrier WITHOUT the implicit vmcnt(0) drain __syncthreads() emits.
__device__ __forceinline__ void wg_barrier() {
    asm volatile("" ::: "memory");
    __builtin_amdgcn_s_barrier();
    asm volatile("" ::: "memory");
}

// ---------------------------------------------------------------------------
// GEMM: C[M,N] = scale * (A[M,K] @ Bt[N,K]^T) + bias
//
// R7 = R6 (8-phase 256x256 template, m201) + TAIL-DRAIN FIX.
// R6's bug: stage_half skips loads for kt>=NT, so in the last iteration
// vmcnt(4) at ph4 left the final tile's B halves (staged ph1/ph2) in flight
// while the next phase read them -> race on the last K-tile of every GEMM.
// Fix: per-K-tile loop; ph4 wait is vmcnt(0) when u+2 >= NT (pipeline ahead
// empty), vmcnt(4) otherwise.
//
// Steady-state ledger (in-order vmcnt retirement), tile u in buf(u&1):
//   ph1: RD_A(0) RD_B(0) | stage B(u+1).lo   ph2: RD_A(1) | stage B(u+1).hi
//   ph3: RD_B(1)         | stage A(u+2).lo   ph4:         | stage A(u+2).hi
//   at ph4: outstanding = {A(u+1).lo/hi [prev ph3/4], B(u+1).lo/hi [ph1/2],
//   A(u+2).lo/hi [ph3/4]} = 12 -> vmcnt(4) retires 8 oldest = tile u+1
//   complete before its first read (next ph1, after 2 barriers).
//   WAR: B.lo/hi last read at ph3 (wn-split), A.lo/hi last read at ph2
//   (wm-split); every stage lands >=1 full barrier after its slot drained.
//
// LDS [256][64] bf16 per operand per buffer; 16B-chunk XOR swizzle
// physical_chunk = logical_chunk ^ (row&7): applied to the GLOBAL source on
// staging (DMA forces linear LDS dest) and to the LDS read offset
// (row&7 == lane&7 for all fragment reads). Staging scheme byte-identical
// to the R2 passing kernel.
//
// 16x16x32 layouts (verified m89/m91): A/B operand m(n)=lane&15,
// k=(lane>>4)*8+j ; C/D col=lane&15, row=(lane>>4)*4+reg.
// ---------------------------------------------------------------------------
template <typename CT, bool BIAS, bool STORE_T = false>
__global__ __launch_bounds__(512, 2)
void gemm_bt(const bf16_t* __restrict__ A, const bf16_t* __restrict__ Bt,
             CT* __restrict__ C, const float* __restrict__ bias,
             int M, int N, int K, float scale,
             size_t sA, size_t sB, size_t sC, int tshift)
{
    __shared__ __align__(16) bf16_t As[2 * 256 * 64];   // 64 KiB (2 buffers)
    __shared__ __align__(16) bf16_t Bs[2 * 256 * 64];   // 64 KiB

    // ---- tile swizzle (XCD remap + bands of 8 by-rows) --------------------
    const int nx = gridDim.x, ny = gridDim.y;
    const int nblk = nx * ny * (int)gridDim.z;
    int lin = blockIdx.x + nx * (blockIdx.y + ny * blockIdx.z);
    int tile = lin;
    if ((nblk & 7) == 0)
        tile = (lin & 7) * (nblk >> 3) + (lin >> 3);
    const int per_z = nx * ny;
    const int bz = tile / per_z;
    int t0 = tile - bz * per_z;
    const int SB = 8;
    const int band = t0 / (nx * SB);
    const int r = t0 - band * (nx * SB);
    const int h = min(SB, ny - band * SB);
    const int bx = r / h;
    const int by = band * SB + (r - bx * h);
    // -----------------------------------------------------------------------

    A  += (size_t)bz * sA;
    Bt += (size_t)bz * sB;
    C  += (size_t)bz * sC;

    const int tid  = threadIdx.x;          // 0..511
    const int wave = tid >> 6;
    const int lane = tid & 63;
    const int m0 = by * 256;
    const int n0 = bx * 256;

    // ---- staging addressing (identical to verified R2 scheme) -------------
    // thread tid covers row (tid>>3) of each 64-row pass, physical chunk
    // tid&7 holding logical chunk (tid&7)^((tid>>3)&7).
    const int srow = tid >> 3;                          // 0..63
    const int lc8  = ((tid & 7) ^ (srow & 7)) * 8;      // logical col (elems)
    const bf16_t* Ag = A  + (size_t)(m0 + srow) * K + lc8;
    const bf16_t* Bg = Bt + (size_t)(n0 + srow) * K + lc8;
    const size_t h64 = (size_t)64 * K;                  // 64-row stride
    const int sbase = wave * 512;                       // elems; +lane*16B auto

    // ---- fragment addressing (16x16x32) -----------------------------------
    const int wm = wave >> 2;              // 0..1 -> rows wm*128..+128
    const int wn = wave & 3;               // 0..3 -> cols wn*64..+64
    const int fl = lane & 15;              // row within 16-frag
    const int fh = lane >> 4;              // 0..3 -> k chunk / C row group
    const int rsw = lane & 7;              // row&7 for swizzle (bases 0 mod 8)

    f32x4_t acc[8][4];
#pragma unroll
    for (int i = 0; i < 8; ++i)
#pragma unroll
        for (int j = 0; j < 4; ++j)
            acc[i][j] = (f32x4_t)(0.f);

    const int NT = K >> 6;                 // K-tiles of 64

    // stage one 16KB half-tile (128 rows) of operand op (0=A,1=B), K-tile kt
    auto stage_half = [&](int op, int kt, int hh) {
        if (kt >= NT) return;
        const bf16_t* src = (op ? Bg : Ag) + (size_t)kt * 64 + (size_t)(hh * 2) * h64;
        bf16_t* dst = (op ? Bs : As) + ((kt & 1) * 16384 + hh * 8192 + sbase);
        gload_lds16(src, dst);                 // rows 0..63 of half
        gload_lds16(src + h64, dst + 4096);    // rows 64..127
    };

    bf16x8_t af[2][4][2];   // [qm][mi][kk], read ph1/ph2, consumed to ph3/ph4
    bf16x8_t bf[2][2];      // [nj][kk], rewritten at ph3

#define RD_A(QM, BO)                                                           \
    _Pragma("unroll") for (int mi = 0; mi < 4; ++mi)                           \
    _Pragma("unroll") for (int kk = 0; kk < 2; ++kk)                           \
        af[QM][mi][kk] = *(const bf16x8_t*)&As[(BO) +                          \
            (wm * 128 + (QM) * 64 + mi * 16 + fl) * 64 +                       \
            ((kk * 4 + fh) ^ rsw) * 8];

#define RD_B(QN, BO)                                                           \
    _Pragma("unroll") for (int nj = 0; nj < 2; ++nj)                           \
    _Pragma("unroll") for (int kk = 0; kk < 2; ++kk)                           \
        bf[nj][kk] = *(const bf16x8_t*)&Bs[(BO) +                              \
            (wn * 64 + (QN) * 32 + nj * 16 + fl) * 64 +                        \
            ((kk * 4 + fh) ^ rsw) * 8];

#define MM(QM, QN)                                                             \
    __builtin_amdgcn_s_setprio(1);                                             \
    _Pragma("unroll") for (int mi = 0; mi < 4; ++mi)                           \
    _Pragma("unroll") for (int nj = 0; nj < 2; ++nj)                           \
    _Pragma("unroll") for (int kk = 0; kk < 2; ++kk)                           \
        acc[(QM) * 4 + mi][(QN) * 2 + nj] =                                    \
            __builtin_amdgcn_mfma_f32_16x16x32_bf16(                           \
                af[QM][mi][kk], bf[nj][kk],                                    \
                acc[(QM) * 4 + mi][(QN) * 2 + nj], 0, 0, 0);                   \
    __builtin_amdgcn_s_setprio(0);

#define LGKM0_PIN()                                                            \
    asm volatile("s_waitcnt lgkmcnt(0)" ::: "memory");                         \
    __builtin_amdgcn_sched_barrier(0);

    // ---- prologue: tile0 (A+B) + tile1 A; drain tile0 (8 oldest of 12) ----
    stage_half(0, 0, 0); stage_half(0, 0, 1);
    stage_half(1, 0, 0); stage_half(1, 0, 1);
    stage_half(0, 1, 0); stage_half(0, 1, 1);
    asm volatile("s_waitcnt vmcnt(4)" ::: "memory");
    __builtin_amdgcn_sched_barrier(0);
    wg_barrier();

    for (int u = 0; u < NT; ++u) {
        const int bo = (u & 1) * 16384;

        // ph1
        RD_A(0, bo)
        RD_B(0, bo)
        stage_half(1, u + 1, 0);
        asm volatile("s_waitcnt lgkmcnt(8)" ::: "memory");
        wg_barrier();
        LGKM0_PIN()
        MM(0, 0)
        wg_barrier();

        // ph2
        RD_A(1, bo)
        stage_half(1, u + 1, 1);
        wg_barrier();
        LGKM0_PIN()
        MM(1, 0)
        wg_barrier();

        // ph3
        RD_B(1, bo)
        stage_half(0, u + 2, 0);
        wg_barrier();
        LGKM0_PIN()
        MM(0, 1)
        wg_barrier();

        // ph4 -- TAIL FIX: when the pipeline ahead is empty (u+2 >= NT, the
        // ph3/ph4 stages were skipped), vmcnt(4) would leave tile u+1's B
        // halves in flight; drain fully instead.
        stage_half(0, u + 2, 1);
        if (u + 2 < NT) {
            asm volatile("s_waitcnt vmcnt(4)" ::: "memory");
        } else {
            asm volatile("s_waitcnt vmcnt(0)" ::: "memory");
        }
        __builtin_amdgcn_sched_barrier(0);
        wg_barrier();
        MM(1, 1)
        wg_barrier();
    }

#undef RD_A
#undef RD_B
#undef MM
#undef LGKM0_PIN

    // ---- epilogue: C/D col=lane&15, row=(lane>>4)*4+reg (verified) --------
#pragma unroll
    for (int nf = 0; nf < 4; ++nf) {
        const int col = n0 + wn * 64 + nf * 16 + fl;
        const float bv = BIAS ? bias[col] : 0.0f;
#pragma unroll
        for (int mf = 0; mf < 8; ++mf) {
            f32x4_t v = acc[mf][nf];
            const int row0 = m0 + wm * 128 + mf * 16 + fh * 4;
            if constexpr (STORE_T) {
                // 4 consecutive rows = 4 consecutive l's of one VT row
                const int b = row0 >> tshift;
                const int l = row0 & ((1 << tshift) - 1);
                bf16x4_t o;
#pragma unroll
                for (int rr2 = 0; rr2 < 4; ++rr2)
                    o[rr2] = (bf16_t)(v[rr2] * scale + bv);
                *(bf16x4_t*)((bf16_t*)C + ((size_t)b * N << tshift) +
                             ((size_t)col << tshift) + l) = o;
            } else {
#pragma unroll
                for (int rr2 = 0; rr2 < 4; ++rr2) {
                    float val = v[rr2] * scale + bv;
                    C[(size_t)(row0 + rr2) * N + col] = (CT)val;
                }
            }
        }
    }
}

// ---------------------------------------------------------------------------
// LayerNorm: one wave per row, D = NV*256 (NV float4 per lane). fp32 in,
// bf16 out.
// ---------------------------------------------------------------------------
template <int NV>
__global__ __launch_bounds__(256, 4)
void layernorm_k(const float* __restrict__ x, const float* __restrict__ g,
                 const float* __restrict__ b, bf16_t* __restrict__ y)
{
    const int D = NV * 256;
    const int wave = threadIdx.x >> 6, lane = threadIdx.x & 63;
    const size_t row = (size_t)blockIdx.x * 4 + wave;
    const float4* xr = (const float4*)(x + row * D);

    float4 v[NV];
    float s = 0.f, sq = 0.f;
#pragma unroll
    for (int i = 0; i < NV; ++i) {
        v[i] = xr[lane + 64 * i];
        s  += v[i].x + v[i].y + v[i].z + v[i].w;
        sq += v[i].x * v[i].x + v[i].y * v[i].y + v[i].z * v[i].z + v[i].w * v[i].w;
    }
#pragma unroll
    for (int m = 32; m; m >>= 1) {
        s  += __shfl_xor(s, m, 64);
        sq += __shfl_xor(sq, m, 64);
    }
    const float mean = s / D;
    const float rstd = rsqrtf(fmaxf(sq / D - mean * mean, 0.f) + 1e-5f);

#pragma unroll
    for (int i = 0; i < NV; ++i) {
        const int c4 = lane + 64 * i;
        float4 gg = ((const float4*)g)[c4];
        float4 bb = ((const float4*)b)[c4];
        bf16x4_t o;
        o[0] = (bf16_t)((v[i].x - mean) * rstd * gg.x + bb.x);
        o[1] = (bf16_t)((v[i].y - mean) * rstd * gg.y + bb.y);
        o[2] = (bf16_t)((v[i].z - mean) * rstd * gg.z + bb.z);
        o[3] = (bf16_t)((v[i].w - mean) * rstd * gg.w + bb.w);
        *(bf16x4_t*)(y + row * D + (size_t)c4 * 4) = o;
    }
}

// ---------------------------------------------------------------------------
// In-place row softmax over 2048 bf16 entries; one wave per row.
// ---------------------------------------------------------------------------
__global__ __launch_bounds__(256, 4)
void softmax_rows(bf16_t* __restrict__ a)
{
    const int wave = threadIdx.x >> 6, lane = threadIdx.x & 63;
    const size_t row = (size_t)blockIdx.x * 4 + wave;
    bf16_t* r = a + row * 2048;

    float v[32];
    float mx = -3.0e38f;
#pragma unroll
    for (int i = 0; i < 4; ++i) {
        bf16x8_t t = *(const bf16x8_t*)(r + (size_t)(lane + 64 * i) * 8);
#pragma unroll
        for (int j = 0; j < 8; ++j) {
            v[i * 8 + j] = (float)t[j];
            mx = fmaxf(mx, v[i * 8 + j]);
        }
    }
#pragma unroll
    for (int m = 32; m; m >>= 1) mx = fmaxf(mx, __shfl_xor(mx, m, 64));
    float s = 0.f;
#pragma unroll
    for (int i = 0; i < 32; ++i) { v[i] = __expf(v[i] - mx); s += v[i]; }
#pragma unroll
    for (int m = 32; m; m >>= 1) s += __shfl_xor(s, m, 64);
    const float rs = 1.0f / s;
#pragma unroll
    for (int i = 0; i < 4; ++i) {
        bf16x8_t t;
#pragma unroll
        for (int j = 0; j < 8; ++j) t[j] = (bf16_t)(v[i * 8 + j] * rs);
        *(bf16x8_t*)(r + (size_t)(lane + 64 * i) * 8) = t;
    }
}

// ---------------------------------------------------------------------------
// fp32 weight [K][N] -> bf16 transposed [N][K]. 32x32 LDS tile.
// ---------------------------------------------------------------------------
__global__ __launch_bounds__(256, 4)
void wconvT(const float* __restrict__ w, bf16_t* __restrict__ wt, int K, int N)
{
    __shared__ float s[32][33];
    const int tx = threadIdx.x, ty = threadIdx.y;   // block (32,8)
    const int n0 = blockIdx.x * 32, k0 = blockIdx.y * 32;
#pragma unroll
    for (int r = 0; r < 4; ++r)
        s[ty + r * 8][tx] = w[(size_t)(k0 + ty + r * 8) * N + n0 + tx];
    __syncthreads();
#pragma unroll
    for (int r = 0; r < 4; ++r)
        wt[(size_t)(n0 + ty + r * 8) * K + k0 + tx] = (bf16_t)s[tx][ty + r * 8];
}

// ---------------------------------------------------------------------------

extern "C" void kernel_launch(void* const* d_in, const int* in_sizes, int n_in,
                              void* d_out, int out_size, void* d_ws, size_t ws_size,
                              hipStream_t stream)
{
    const int B = 8, L1 = 2048, L2 = 2048, D1 = 1024, D2 = 768, E = 1024;
    const float scale = 0.03125f;  // E^-0.5
    const int tsh = 11;            // log2(L2)

    const float* m1   = (const float*)d_in[0];
    const float* m2   = (const float*)d_in[1];
    const float* ln1g = (const float*)d_in[2];
    const float* ln1b = (const float*)d_in[3];
    const float* ln2g = (const float*)d_in[4];
    const float* ln2b = (const float*)d_in[5];
    const float* Wq   = (const float*)d_in[6];
    const float* bq   = (const float*)d_in[7];
    const float* Wk   = (const float*)d_in[8];
    const float* bk   = (const float*)d_in[9];
    const float* Wv   = (const float*)d_in[10];
    const float* bv   = (const float*)d_in[11];
    const float* Wo   = (const float*)d_in[12];
    const float* bo   = (const float*)d_in[13];
    float* out = (float*)d_out;

    bf16_t* ws = (bf16_t*)d_ws;
    size_t off = 0;
    auto alloc = [&](size_t n) { bf16_t* p = ws + off; off += n; return p; };
    bf16_t* WqT = alloc((size_t)E * D1);
    bf16_t* WkT = alloc((size_t)E * D2);
    bf16_t* WvT = alloc((size_t)E * D2);
    bf16_t* WoT = alloc((size_t)D1 * E);
    bf16_t* x1  = alloc((size_t)B * L1 * D1);
    bf16_t* x2  = alloc((size_t)B * L2 * D2);
    bf16_t* Qb  = alloc((size_t)B * L1 * E);
    bf16_t* Kb  = alloc((size_t)B * L2 * E);
    bf16_t* VTb = alloc((size_t)B * E * L2);   // V^T, written directly by proj
    bf16_t* ctx = alloc((size_t)B * L1 * E);
    bf16_t* attn = ws + off;
    const bool batched = (off + (size_t)B * L1 * L2) * sizeof(bf16_t) <= ws_size;

    dim3 blk256(256);
    dim3 blk512(512);

    // 1. weights -> bf16 transposed
    wconvT<<<dim3(E / 32, D1 / 32), dim3(32, 8), 0, stream>>>(Wq, WqT, D1, E);
    wconvT<<<dim3(E / 32, D2 / 32), dim3(32, 8), 0, stream>>>(Wk, WkT, D2, E);
    wconvT<<<dim3(E / 32, D2 / 32), dim3(32, 8), 0, stream>>>(Wv, WvT, D2, E);
    wconvT<<<dim3(D1 / 32, E / 32), dim3(32, 8), 0, stream>>>(Wo, WoT, E, D1);

    // 2. layernorms -> bf16
    layernorm_k<4><<<dim3(B * L1 / 4), blk256, 0, stream>>>(m1, ln1g, ln1b, x1);
    layernorm_k<3><<<dim3(B * L2 / 4), blk256, 0, stream>>>(m2, ln2g, ln2b, x2);

    // 3. projections (V writes V^T directly via STORE_T epilogue)
    gemm_bt<bf16_t, true><<<dim3(E / 256, B * L1 / 256, 1), blk512, 0, stream>>>(
        x1, WqT, Qb, bq, B * L1, E, D1, 1.0f, 0, 0, 0, 0);
    gemm_bt<bf16_t, true><<<dim3(E / 256, B * L2 / 256, 1), blk512, 0, stream>>>(
        x2, WkT, Kb, bk, B * L2, E, D2, 1.0f, 0, 0, 0, 0);
    gemm_bt<bf16_t, true, true><<<dim3(E / 256, B * L2 / 256, 1), blk512, 0, stream>>>(
        x2, WvT, VTb, bv, B * L2, E, D2, 1.0f, 0, 0, 0, tsh);

    // 4. attention
    if (batched) {
        gemm_bt<bf16_t, false><<<dim3(L2 / 256, L1 / 256, B), blk512, 0, stream>>>(
            Qb, Kb, attn, nullptr, L1, L2, E, scale,
            (size_t)L1 * E, (size_t)L2 * E, (size_t)L1 * L2, 0);
        softmax_rows<<<dim3(B * L1 / 4), blk256, 0, stream>>>(attn);
        gemm_bt<bf16_t, false><<<dim3(E / 256, L1 / 256, B), blk512, 0, stream>>>(
            attn, VTb, ctx, nullptr, L1, E, L2, 1.0f,
            (size_t)L1 * L2, (size_t)E * L2, (size_t)L1 * E, 0);
    } else {
        for (int b = 0; b < B; ++b) {
            gemm_bt<bf16_t, false><<<dim3(L2 / 256, L1 / 256, 1), blk512, 0, stream>>>(
                Qb + (size_t)b * L1 * E, Kb + (size_t)b * L2 * E, attn, nullptr,
                L1, L2, E, scale, 0, 0, 0, 0);
            softmax_rows<<<dim3(L1 / 4), blk256, 0, stream>>>(attn);
            gemm_bt<bf16_t, false><<<dim3(E / 256, L1 / 256, 1), blk512, 0, stream>>>(
                attn, VTb + (size_t)b * E * L2, ctx + (size_t)b * L1 * E, nullptr,
                L1, E, L2, 1.0f, 0, 0, 0, 0);
        }
    }

    // 5. output projection -> fp32 d_out
    gemm_bt<float, true><<<dim3(D1 / 256, B * L1 / 256, 1), blk512, 0, stream>>>(
        ctx, WoT, out, bo, B * L1, D1, E, 1.0f, 0, 0, 0, 0);
}